// Round 3
// baseline (990.492 us; speedup 1.0000x reference)
//
#include <hip/hip_runtime.h>
#include <hip/hip_bf16.h>

// Two-phase: (1) bit-pack x rows via wave ballot (stream-bound, 784 MB),
// (2) traverse from LDS-resident packed rows (latency-light).
//
// W = 784 features -> 13 u64 words per row; padded to 16 u64 (128 B) in d_ws.

#define W_FEAT    784
#define NW64      13     // ceil(784/64)
#define ROW_U64   16     // padded row stride (128 B)
#define LDS_STRIDE 33    // dwords per row in LDS (32 + 1 pad -> banks = tid + word)

__global__ __launch_bounds__(256) void tree_pack_kernel(
    const int* __restrict__ x,
    unsigned long long* __restrict__ packed,
    int n)
{
    const int row_i = (blockIdx.x * blockDim.x + threadIdx.x) >> 6; // one wave per row
    const int lane  = threadIdx.x & 63;
    if (row_i >= n) return;

    const int* __restrict__ row = x + (long long)row_i * W_FEAT;
    unsigned long long* __restrict__ orow = packed + (long long)row_i * ROW_U64;

    unsigned long long myv = 0;
    #pragma unroll
    for (int k = 0; k < NW64; ++k) {
        const int idx = k * 64 + lane;
        int v = 0;
        if (idx < W_FEAT) v = row[idx];          // coalesced 256 B per instr
        const unsigned long long b = __ballot(v & 1);
        if (lane == k) myv = b;                  // static lane->word assignment
    }
    if (lane < NW64) orow[lane] = myv;           // coalesced 104 B store
    // words 13..15 of the padded row are never read by traversal (c>>6 <= 12)
}

__global__ __launch_bounds__(256) void tree_traverse_kernel(
    const unsigned long long* __restrict__ packed,
    const int* __restrict__ choices,
    const float* __restrict__ preds,
    const int* __restrict__ depth_p,
    int* __restrict__ out,
    int n)
{
    __shared__ unsigned int lds[256 * LDS_STRIDE];   // 33,792 B -> 4 blocks/CU

    const int tid  = threadIdx.x;
    const int base = blockIdx.x * 256;

    // Coalesced copy: 256 rows x 128 B  global -> LDS (stride 33 dwords)
    const uint4* __restrict__ gp = (const uint4*)packed;  // 8 uint4 per padded row
    #pragma unroll
    for (int it = 0; it < 8; ++it) {
        const int idx = it * 256 + tid;      // [0, 2048)
        const int r   = idx >> 3;            // row within block
        const int c4  = idx & 7;             // 16B chunk within row
        if (base + r < n) {
            const uint4 v = gp[(long long)(base + r) * 8 + c4];
            unsigned int* dst = &lds[r * LDS_STRIDE + c4 * 4];
            dst[0] = v.x; dst[1] = v.y; dst[2] = v.z; dst[3] = v.w;
        }
    }
    __syncthreads();

    const int i = base + tid;
    if (i >= n) return;

    const int depth = *depth_p;                          // uniform (=15)
    const unsigned int* __restrict__ row = &lds[tid * LDS_STRIDE];

    int node = 0;
    for (int d = 0; d < depth; ++d) {
        const int c   = choices[node];                   // L2-resident (256 KB)
        const int bit = (row[c >> 5] >> (c & 31)) & 1;   // LDS, ~2-way bank alias
        node = node * 2 + bit + 1;
    }
    out[i] = (preds[node] != 0.0f) ? 1 : 0;              // bool as int32
}

extern "C" void kernel_launch(void* const* d_in, const int* in_sizes, int n_in,
                              void* d_out, int out_size, void* d_ws, size_t ws_size,
                              hipStream_t stream) {
    const int*   x       = (const int*)d_in[0];
    const int*   choices = (const int*)d_in[1];
    const float* preds   = (const float*)d_in[2];
    const int*   depth_p = (const int*)d_in[3];
    int*         out     = (int*)d_out;

    const int n = out_size;                 // 250000 samples
    unsigned long long* packed = (unsigned long long*)d_ws;  // 250000*128 B = 32 MB

    // Phase 1: pack. One wave per row -> 4 rows per 256-thread block.
    const int pack_blocks = (n + 3) / 4;
    tree_pack_kernel<<<pack_blocks, 256, 0, stream>>>(x, packed, n);

    // Phase 2: traverse. One thread per row.
    const int trav_blocks = (n + 255) / 256;
    tree_traverse_kernel<<<trav_blocks, 256, 0, stream>>>(
        packed, choices, preds, depth_p, out, n);
}

// Round 4
// 975.766 us; speedup vs baseline: 1.0151x; 1.0151x over previous
//
#include <hip/hip_runtime.h>
#include <hip/hip_bf16.h>

// Fused: each block ballot-packs its 256 rows of x (784 KB coalesced stream)
// into LDS bitmaps, then traverses the tree from LDS + L2-resident tables.
// HBM traffic: 784 MB read (x) + ~1 MB write (out). No workspace round-trip.

#define W_FEAT 784
#define NW64   13    // ceil(784/64) u64 words per packed row
#define LSTR   27    // u32 stride per row in LDS (26 used + 1 pad; odd -> 2-way alias = free)

__global__ __launch_bounds__(256) void tree_fused_kernel(
    const int* __restrict__ x,
    const int* __restrict__ choices,
    const float* __restrict__ preds,
    const int* __restrict__ depth_p,
    int* __restrict__ out,
    int n)
{
    __shared__ unsigned int lds[256 * LSTR];   // 27,648 B -> 5 blocks/CU by LDS

    const int tid  = threadIdx.x;
    const int wave = tid >> 6;
    const int lane = tid & 63;
    const int base = blockIdx.x * 256;

    // ---- Phase A: each wave packs 64 rows via ballot ----
    const int rbase = base + wave * 64;
    for (int r = 0; r < 64; ++r) {
        const int g = rbase + r;
        if (g >= n) break;                     // wave-uniform exit
        const int* __restrict__ row = x + (long long)g * W_FEAT;

        // 13 independent coalesced loads first (one waitcnt per row, not 13)
        int v[NW64];
        #pragma unroll
        for (int k = 0; k < NW64; ++k) {
            const int idx = k * 64 + lane;
            v[k] = (idx < W_FEAT) ? row[idx] : 0;
        }

        unsigned int* __restrict__ dst = &lds[(wave * 64 + r) * LSTR];
        #pragma unroll
        for (int k = 0; k < NW64; ++k) {
            const unsigned long long b = __ballot(v[k] & 1);  // bit l = feature k*64+l
            if (lane == k) {
                dst[2 * k]     = (unsigned int)(b);
                dst[2 * k + 1] = (unsigned int)(b >> 32);
            }
        }
    }
    __syncthreads();

    // ---- Phase B: one thread per sample, traverse from LDS bitmap ----
    const int i = base + tid;
    if (i >= n) return;

    const int depth = *depth_p;                          // uniform (=15)
    const unsigned int* __restrict__ row = &lds[tid * LSTR];

    int node = 0;
    for (int d = 0; d < depth; ++d) {
        const int c   = choices[node];                   // 256 KB table, L2-resident
        const int bit = (row[c >> 5] >> (c & 31)) & 1;   // LDS bit lookup
        node = node * 2 + bit + 1;
    }
    out[i] = (preds[node] != 0.0f) ? 1 : 0;              // bool as int32
}

extern "C" void kernel_launch(void* const* d_in, const int* in_sizes, int n_in,
                              void* d_out, int out_size, void* d_ws, size_t ws_size,
                              hipStream_t stream) {
    const int*   x       = (const int*)d_in[0];
    const int*   choices = (const int*)d_in[1];
    const float* preds   = (const float*)d_in[2];
    const int*   depth_p = (const int*)d_in[3];
    int*         out     = (int*)d_out;

    const int n = out_size;                 // 250000 samples
    const int blocks = (n + 255) / 256;     // 977
    tree_fused_kernel<<<blocks, 256, 0, stream>>>(
        x, choices, preds, depth_p, out, n);
}

// Round 5
// 913.327 us; speedup vs baseline: 1.0845x; 1.0684x over previous
//
#include <hip/hip_runtime.h>
#include <hip/hip_bf16.h>

// Naive gather traversal (byte-optimal: ~13 distinct 64B lines/row vs 784B/row
// for any streaming scheme), with both-children choice prefetch so the L2
// choices lookup hides under the HBM bit gather each level.
//
// x:      [N, 784] int32 binary features (row-major)
// choices:[65537] int32 (256 KB, L2-resident)
// preds:  [65537] float32
// out:    [N] int32 (bool)

#define W_FEAT 784

__global__ __launch_bounds__(256) void tree_kernel(
    const int* __restrict__ x,
    const int* __restrict__ choices,
    const float* __restrict__ preds,
    const int* __restrict__ depth_p,
    int* __restrict__ out,
    int n)
{
    const int i = blockIdx.x * blockDim.x + threadIdx.x;
    if (i >= n) return;

    const int depth = *depth_p;                       // uniform (=15)
    const int* __restrict__ row = x + (long long)i * W_FEAT;

    int node = 0;
    int c = choices[0];                               // level-0 feature (uniform)
    for (int d = 0; d < depth; ++d) {
        const int bit = row[c];                       // HBM gather (~900 cyc)
        const int l   = node * 2 + 1;
        const int cl  = choices[l];                   // L2 (~250 cyc) — both issued
        const int cr  = choices[l + 1];               //   before waiting on `bit`
        node = l + bit;
        c    = bit ? cr : cl;                         // select, no extra load
    }
    out[i] = (preds[node] != 0.0f) ? 1 : 0;           // bool as int32
}

extern "C" void kernel_launch(void* const* d_in, const int* in_sizes, int n_in,
                              void* d_out, int out_size, void* d_ws, size_t ws_size,
                              hipStream_t stream) {
    const int*   x       = (const int*)d_in[0];
    const int*   choices = (const int*)d_in[1];
    const float* preds   = (const float*)d_in[2];
    const int*   depth_p = (const int*)d_in[3];
    int*         out     = (int*)d_out;

    const int n = out_size;                 // 250000
    const int block = 256;
    const int grid  = (n + block - 1) / block;
    tree_kernel<<<grid, block, 0, stream>>>(x, choices, preds, depth_p, out, n);
}